// Round 5
// baseline (372.247 us; speedup 1.0000x reference)
//
#include <hip/hip_runtime.h>

// MHA: cvt fp32->bf16 -> QKV GEMM (256^2 8-phase-style bf16 MFMA, fused RoPE)
//      -> MFMA flash attention (fp32 out)
// B=2 S=2048 E=2048 NH=16 HD=128 ROTARY=32 base=1e4 NEG_INF=-1e4
#define B_    2
#define S_    2048
#define E_    2048
#define NH_   16
#define HD_   128
#define NQKV_ 6144
#define M_    4096
#define XN_   (M_ * E_)          // 8388608 X elements
#define NPAN  (E_ / 32)          // 64 K-panels of 32

typedef short bf16x8 __attribute__((ext_vector_type(8)));   // 8 bf16 (4 VGPRs)
typedef float f32x4  __attribute__((ext_vector_type(4)));   // MFMA C/D

typedef const __attribute__((address_space(1))) void* gas_t; // global addrspace
typedef __attribute__((address_space(3))) void*       las_t; // LDS addrspace

__device__ inline float b2f(unsigned short u) {
    return __uint_as_float(((unsigned int)u) << 16);
}
__device__ inline unsigned short f2b(float f) {             // RNE f32->bf16
    unsigned int x = __float_as_uint(f);
    x = x + 0x7fffu + ((x >> 16) & 1u);
    return (unsigned short)(x >> 16);
}
__device__ inline unsigned int pk2(float lo, float hi) {
    return (unsigned int)f2b(lo) | ((unsigned int)f2b(hi) << 16);
}

// ---------------------------------------------------------------------------
// Kernel 0: one-shot fp32 -> bf16 of X (8.39M) and W (12.58M) into workspace.
// ---------------------------------------------------------------------------
__global__ __launch_bounds__(256) void cvt_bf16(
    const float* __restrict__ X,
    const float* __restrict__ W,
    unsigned short* __restrict__ O)      // [XN_ of X][W follows]
{
    const long i = (long)(blockIdx.x * 256 + threadIdx.x) * 8;
    const float* src = (i < XN_) ? (X + i) : (W + (i - XN_));
    const float4 a = *(const float4*)(src);
    const float4 b = *(const float4*)(src + 4);
    uint4 o = { pk2(a.x, a.y), pk2(a.z, a.w), pk2(b.x, b.y), pk2(b.z, b.w) };
    *(uint4*)(O + i) = o;
}

// ---------------------------------------------------------------------------
// Kernel 1: QKV = Xb(4096x2048 bf16) * Wb^T + bias, RoPE fused in epilogue.
// 256x256 tile, 512 threads (8 waves, 2M x 4N), K in 32-wide panels,
// 4 LDS slots (128 KiB), 2 phases per panel.
// ROUND-5 FIXES vs failed round-4:
//  (a) RoPE: BN=256 spans TWO heads; rotate wc==0 AND wc==2 (was wc==0 only
//      -> head B never rotated -> absmax 1.14).
//  (b) vmcnt invariant: counted wait must precede the ds_reads it guards.
//      Invariant "A/B(p) landed in all waves before any wave reads panel p"
//      is established at panel p-1 phase 1: after stageB(p+2) the 8 newest
//      outstanding loads are A/B(p+1),A/B(p+2) -> vmcnt(8) + barrier
//      guarantees A/B(p). Prologue vmcnt(0)+barrier seeds panels 0..2.
//      (Round-4 put vmcnt(10) AFTER the phase-0 ds_reads -> stale-LDS race.)
// LDS layout: [row][4 k-octets of 16B], octet slot ko' = ko ^ ((row>>1)&3),
// applied on the global SOURCE address (global_load_lds writes linearly) and
// on the ds_read address (both-sides involution) -> fragment b128 reads hit
// 8 distinct bank groups (2 lanes/bank = free) instead of 2.
// WAR safety: stage(p+3) writes slot (p-1)&3; panel p-1's ds_reads are
// lgkm-retired before its closing barrier; stage issues after that barrier.
// ---------------------------------------------------------------------------
__global__ __launch_bounds__(512, 2) void qkv_gemm(
    const unsigned short* __restrict__ Xb,   // bf16 [4096][2048]
    const unsigned short* __restrict__ Wb,   // bf16 [6144][2048]
    const float* __restrict__ bias,
    unsigned short* __restrict__ qb,
    unsigned short* __restrict__ kb,
    unsigned short* __restrict__ vb)
{
    __shared__ __align__(16) unsigned short As[4][256 * 32];  // 64 KiB
    __shared__ __align__(16) unsigned short Bs[4][256 * 32];  // 64 KiB

    const int t    = threadIdx.x;            // 0..511
    const int lane = t & 63;
    const int w    = t >> 6;                 // 0..7
    const int wr   = w >> 2;                 // 0..1  (m half)
    const int wc   = w & 3;                  // 0..3  (n quarter)
    const int quad = (lane >> 4) & 3;
    const int l16  = lane & 15;

    // XCD-aware bijective swizzle: 384 = 8 * 48
    const int wg = ((int)blockIdx.x & 7) * 48 + ((int)blockIdx.x >> 3);
    const int m0 = (wg / 24) * 256;
    const int n0 = (wg % 24) * 256;

    // --- staging: one panel (256 rows x 32 k) = 2 block-calls of 8 KB.
    // call c, wave w covers 16B-units u = c*512 + w*64 + lane;
    // unit u -> (row = u>>2, koLDS = u&3); global k-octet = koLDS ^ ((row>>1)&3).
    auto stageA = [&](int p) {
        const int sl = p & 3;
        const int k0 = p * 32;
        #pragma unroll
        for (int c = 0; c < 2; c++) {
            const int ub  = c * 512 + w * 64;
            const int u   = ub + lane;
            const int row = u >> 2;
            const int ko  = (u & 3) ^ ((row >> 1) & 3);
            __builtin_amdgcn_global_load_lds(
                (gas_t)(Xb + (size_t)(m0 + row) * E_ + k0 + ko * 8),
                (las_t)&As[sl][ub * 8], 16, 0, 0);
        }
    };
    auto stageB = [&](int p) {
        const int sl = p & 3;
        const int k0 = p * 32;
        #pragma unroll
        for (int c = 0; c < 2; c++) {
            const int ub  = c * 512 + w * 64;
            const int u   = ub + lane;
            const int row = u >> 2;
            const int ko  = (u & 3) ^ ((row >> 1) & 3);
            __builtin_amdgcn_global_load_lds(
                (gas_t)(Wb + (size_t)(n0 + row) * E_ + k0 + ko * 8),
                (las_t)&Bs[sl][ub * 8], 16, 0, 0);
        }
    };

    f32x4 acc[8][4];
    #pragma unroll
    for (int i = 0; i < 8; i++)
        #pragma unroll
        for (int j = 0; j < 4; j++)
            #pragma unroll
            for (int r = 0; r < 4; r++) acc[i][j][r] = 0.0f;

    // prologue: stage panels 0..2, full drain once -> panels 0..2 landed
    stageA(0); stageB(0);
    stageA(1); stageB(1);
    stageA(2); stageB(2);
    asm volatile("s_waitcnt vmcnt(0)" ::: "memory");
    __builtin_amdgcn_s_barrier();

    for (int p = 0; p < NPAN; p++) {
        const int sl = p & 3;
        bf16x8 af[4], bf[4];

        // ---- phase 0: A(mh=0) + B frags (panel p valid by invariant),
        //      stage A(p+3)
        #pragma unroll
        for (int mf = 0; mf < 4; mf++) {
            const int row = wr * 128 + mf * 16 + l16;
            af[mf] = *(const bf16x8*)&As[sl][row * 32 + (quad ^ ((row >> 1) & 3)) * 8];
        }
        #pragma unroll
        for (int nf = 0; nf < 4; nf++) {
            const int rb = wc * 64 + nf * 16 + l16;
            bf[nf] = *(const bf16x8*)&Bs[sl][rb * 32 + (quad ^ ((rb >> 1) & 3)) * 8];
        }
        if (p + 3 < NPAN) stageA(p + 3);
        __builtin_amdgcn_s_barrier();
        __builtin_amdgcn_s_setprio(1);
        #pragma unroll
        for (int mf = 0; mf < 4; mf++)
            #pragma unroll
            for (int nf = 0; nf < 4; nf++)
                acc[mf][nf] = __builtin_amdgcn_mfma_f32_16x16x32_bf16(
                    af[mf], bf[nf], acc[mf][nf], 0, 0, 0);
        __builtin_amdgcn_s_setprio(0);
        __builtin_amdgcn_s_barrier();

        // ---- phase 1: A(mh=1) frags (B reused from regs), stage B(p+3),
        //      counted vmcnt establishes invariant for panel p+1
        #pragma unroll
        for (int mf = 0; mf < 4; mf++) {
            const int row = wr * 128 + 64 + mf * 16 + l16;
            af[mf] = *(const bf16x8*)&As[sl][row * 32 + (quad ^ ((row >> 1) & 3)) * 8];
        }
        if (p + 3 < NPAN) stageB(p + 3);
        // newest 8 outstanding: A/B(p+2), A/B(p+3) -> A/B(p+1) complete
        asm volatile("s_waitcnt vmcnt(8)" ::: "memory");
        __builtin_amdgcn_s_barrier();
        __builtin_amdgcn_s_setprio(1);
        #pragma unroll
        for (int mf = 0; mf < 4; mf++)
            #pragma unroll
            for (int nf = 0; nf < 4; nf++)
                acc[4 + mf][nf] = __builtin_amdgcn_mfma_f32_16x16x32_bf16(
                    af[mf], bf[nf], acc[4 + mf][nf], 0, 0, 0);
        __builtin_amdgcn_s_setprio(0);
        __builtin_amdgcn_s_barrier();
    }

    // ---- epilogue: bias, fused RoPE, bf16 scatter stores (no LDS use).
    const int which = n0 >> 11;                   // 0=q 1=k 2=v (const/block)
    unsigned short* dst = (which == 0) ? qb : ((which == 1) ? kb : vb);

    float bv[4];
    #pragma unroll
    for (int nf = 0; nf < 4; nf++) bv[nf] = bias[n0 + wc * 64 + nf * 16 + l16];
    #pragma unroll
    for (int mi = 0; mi < 8; mi++)
        #pragma unroll
        for (int nf = 0; nf < 4; nf++)
            #pragma unroll
            for (int r = 0; r < 4; r++) acc[mi][nf][r] += bv[nf];

    // RoPE: tile spans 2 heads; head-local d<64 quarters are wc==0 (head A)
    // and wc==2 (head B). Pairs (d=l16, d+16) live in acc[mi][0]/acc[mi][1].
    if ((wc & 1) == 0 && which < 2) {
        const float inv = exp2f(-0.83048202372184059f * (float)l16); // 1e4^(-d/16)
        #pragma unroll
        for (int mi = 0; mi < 8; mi++) {
            #pragma unroll
            for (int r = 0; r < 4; r++) {
                const int m = m0 + wr * 128 + (mi >> 2) * 64 + (mi & 3) * 16
                              + quad * 4 + r;
                const int sdx = m & (S_ - 1);
                float c, sn;
                __sincosf((float)sdx * inv, &sn, &c);
                const float u1 = acc[mi][0][r], u2 = acc[mi][1][r];
                acc[mi][0][r] = u1 * c - u2 * sn;
                acc[mi][1][r] = u1 * sn + u2 * c;
            }
        }
    }

    #pragma unroll
    for (int nf = 0; nf < 4; nf++) {
        const int hh = ((n0 + wc * 64 + nf * 16) >> 7) & 15;
        const int d  = ((wc * 64 + nf * 16) & 127) + l16;
        #pragma unroll
        for (int mi = 0; mi < 8; mi++) {
            #pragma unroll
            for (int r = 0; r < 4; r++) {
                const int m   = m0 + wr * 128 + (mi >> 2) * 64 + (mi & 3) * 16
                                + quad * 4 + r;
                const int bb  = m >> 11;
                const int sdx = m & (S_ - 1);
                dst[((size_t)(bb * NH_ + hh) * S_ + sdx) * HD_ + d] =
                    f2b(acc[mi][nf][r]);
            }
        }
    }
}

// ---------------------------------------------------------------------------
// Kernel 2: MFMA causal flash attention (unchanged from round 3 — passing).
// Layouts (HW-verified 16x16x32_bf16): A[m=lane&15][k=quad*8+j];
// C/D row=quad*4+reg, col=lane&15.
// ---------------------------------------------------------------------------
#define KSTR 136
#define VSTR 72
#define PSTR 72
#define OSTR 132

__global__ __launch_bounds__(256, 3) void attn_mfma(
    const unsigned short* __restrict__ qb,
    const unsigned short* __restrict__ kb,
    const unsigned short* __restrict__ vb,
    float* __restrict__ out)
{
    union SM {
        struct {
            unsigned short Ks[64 * KSTR];      // 17408 B
            unsigned short Vt[128 * VSTR];     // 18432 B
            unsigned short Ps[4 * 16 * PSTR];  //  9216 B
        } a;                                   // 45056 B total
        float Ow[4 * 16 * OSTR];               // 33792 B (epilogue reuse)
    };
    __shared__ __align__(16) SM sm;
    unsigned short* Ks = sm.a.Ks;
    unsigned short* Vt = sm.a.Vt;
    unsigned short* Ps = sm.a.Ps;

    const int bid  = blockIdx.x;
    const int qt   = 31 - (bid >> 5);       // 64-row q-tile, heavy-first
    const int bh   = bid & 31;
    const int b    = bh >> 4;
    const int h    = bh & 15;
    const int t    = threadIdx.x;
    const int lane = t & 63;
    const int w    = t >> 6;
    const int quad = lane >> 4;
    const int l16  = lane & 15;

    const int wrow0  = qt * 64 + w * 16;    // wave q-row base (16 rows)
    const int ntiles = qt + 1;              // K tiles of 64

    unsigned short* Pw = Ps + w * 16 * PSTR;

    // staging maps (256 threads)
    const int krow = t >> 2, kcb = (t & 3) * 32;   // K: row, col-block
    const int vq   = t & 31, vd0 = (t >> 5) * 16;  // V: s-pair, d-block

    // Q A-fragments from global: k = c*32 + quad*8 + j
    bf16x8 qf[4];
    {
        const unsigned short* qp =
            qb + ((size_t)(bh * S_ + wrow0 + l16)) * HD_ + quad * 8;
        #pragma unroll
        for (int c = 0; c < 4; c++)
            qf[c] = *(const bf16x8*)(qp + c * 32);
    }

    f32x4 of[8];
    #pragma unroll
    for (int db = 0; db < 8; db++)
        #pragma unroll
        for (int r = 0; r < 4; r++) of[db][r] = 0.0f;
    float mr[4], lr[4];
    #pragma unroll
    for (int r = 0; r < 4; r++) { mr[r] = -1e30f; lr[r] = 0.0f; }

    // log2-domain softmax: scale' = (1/sqrt(128))*log2(e), mask' = -1e4*log2(e)
    const float scale2 = 0.12751744459892879f;
    const float mneg2  = -14426.950408889634f;

    // prefetch registers
    uint4 kr[4];
    uint4 v0a, v0b, v1a, v1b;

    auto issue_tile = [&](int kt2) {
        const int s2 = kt2 * 64;
        const unsigned short* kg = kb + ((size_t)(bh * S_ + s2 + krow)) * HD_ + kcb;
        #pragma unroll
        for (int u = 0; u < 4; u++) kr[u] = *(const uint4*)(kg + u * 8);
        const unsigned short* vg = vb + ((size_t)(bh * S_ + s2 + 2 * vq)) * HD_ + vd0;
        v0a = *(const uint4*)(vg);
        v0b = *(const uint4*)(vg + 8);
        v1a = *(const uint4*)(vg + HD_);
        v1b = *(const uint4*)(vg + HD_ + 8);
    };

    issue_tile(0);

    for (int kt = 0; kt < ntiles; kt++) {
        const int s0 = kt * 64;
        __syncthreads();                  // prior iter's LDS readers done
        // ---- K tile -> LDS (row-major, b128)
        #pragma unroll
        for (int u = 0; u < 4; u++)
            *(uint4*)&Ks[krow * KSTR + kcb + u * 8] = kr[u];
        // ---- V tile -> LDS transposed: Vt[d][s], s-pairs packed as b32
        {
            unsigned int r0[8] = { v0a.x, v0a.y, v0a.z, v0a.w,
                                   v0b.x, v0b.y, v0b.z, v0b.w };
            unsigned int r1[8] = { v1a.x, v1a.y, v1a.z, v1a.w,
                                   v1b.x, v1b.y, v1b.z, v1b.w };
            #pragma unroll
            for (int j = 0; j < 16; j++) {
                const int u = j >> 1;
                unsigned int pk;
                if ((j & 1) == 0)
                    pk = (r0[u] & 0xffffu) | (r1[u] << 16);
                else
                    pk = (r0[u] >> 16) | (r1[u] & 0xffff0000u);
                *(unsigned int*)&Vt[(vd0 + j) * VSTR + 2 * vq] = pk;
            }
        }
        __syncthreads();

        if (kt + 1 < ntiles) issue_tile(kt + 1);

        // ---- S = Q K^T : 4 nb MFMAs
        f32x4 sf[4];
        #pragma unroll
        for (int nb = 0; nb < 4; nb++)
            #pragma unroll
            for (int r = 0; r < 4; r++) sf[nb][r] = 0.0f;
        #pragma unroll
        for (int c = 0; c < 4; c++) {
            #pragma unroll
            for (int nb = 0; nb < 4; nb++) {
                bf16x8 kf = *(const bf16x8*)&Ks[(nb * 16 + l16) * KSTR + c * 32 + quad * 8];
                sf[nb] = __builtin_amdgcn_mfma_f32_16x16x32_bf16(
                    qf[c], kf, sf[nb], 0, 0, 0);
            }
        }

        // ---- scale + causal mask, log2 domain
        const bool need_mask = (s0 + 63 > wrow0);
        {
            const int qr0 = wrow0 + quad * 4;
            #pragma unroll
            for (int nb = 0; nb < 4; nb++) {
                const int kcol = s0 + nb * 16 + l16;
                #pragma unroll
                for (int r = 0; r < 4; r++) {
                    float s = sf[nb][r] * scale2;
                    if (need_mask && kcol > qr0 + r) s += mneg2;
                    sf[nb][r] = s;
                }
            }
        }

        // ---- online softmax (max reduce over 16-lane group; lr partials;
        //      rescale deferred when no row max grew)
        {
            float mt4[4];
            #pragma unroll
            for (int r = 0; r < 4; r++) {
                float mt = fmaxf(fmaxf(sf[0][r], sf[1][r]),
                                 fmaxf(sf[2][r], sf[3][r]));
                mt = fmaxf(mt, __shfl_xor(mt, 1));
                mt = fmaxf(mt, __shfl_xor(mt, 2));
                mt = fmaxf(mt, __shfl_xor(mt, 4));
                mt = fmaxf(mt, __shfl_xor(mt, 8));
                mt4[r] = mt;
            }
            const bool grew = (mt4[0] > mr[0]) || (mt4[1] > mr[1]) ||
                              (mt4[2] > mr[2]) || (mt4[3] > mr[3]);
            if (__any(grew)) {
                float alpha[4];
                #pragma unroll
                for (int r = 0; r < 4; r++) {
                    const float mnew = fmaxf(mr[r], mt4[r]);
                    alpha[r] = __builtin_amdgcn_exp2f(mr[r] - mnew);
                    mr[r] = mnew;
                    lr[r] *= alpha[r];
                }
                #pragma unroll
                for (int db = 0; db < 8; db++)
                    #pragma unroll
                    for (int r = 0; r < 4; r++) of[db][r] *= alpha[r];
            }
            #pragma unroll
            for (int r = 0; r < 4; r++) {
                float rs = 0.0f;
                #pragma unroll
                for (int nb = 0; nb < 4; nb++) {
                    float p = __builtin_amdgcn_exp2f(sf[nb][r] - mr[r]);
                    sf[nb][r] = p;
                    rs += p;
                }
                lr[r] += rs;       // per-lane partial; reduced in epilogue
            }

            // P: C-layout -> wave-private LDS [m][s]
            #pragma unroll
            for (int nb = 0; nb < 4; nb++)
                #pragma unroll
                for (int r = 0; r < 4; r++)
                    Pw[(quad * 4 + r) * PSTR + nb * 16 + l16] = f2b(sf[nb][r]);
        }

        // ---- O += P V
        #pragma unroll
        for (int kc = 0; kc < 2; kc++) {
            bf16x8 pf = *(const bf16x8*)&Pw[l16 * PSTR + kc * 32 + quad * 8];
            #pragma unroll
            for (int db = 0; db < 8; db++) {
                bf16x8 vf = *(const bf16x8*)&Vt[(db * 16 + l16) * VSTR + kc * 32 + quad * 8];
                of[db] = __builtin_amdgcn_mfma_f32_16x16x32_bf16(
                    pf, vf, of[db], 0, 0, 0);
            }
        }
    }

    // ---- epilogue: lane-reduce lr, normalize, LDS transpose, float4 stores.
    float* Ow = sm.Ow + w * 16 * OSTR;     // wave-private 16x132 fp32
    __syncthreads();                       // all readers of Ks/Vt/Ps done
    float inv[4];
    #pragma unroll
    for (int r = 0; r < 4; r++) {
        float ls = lr[r];
        ls += __shfl_xor(ls, 1);
        ls += __shfl_xor(ls, 2);
        ls += __shfl_xor(ls, 4);
        ls += __shfl_xor(ls, 8);
        inv[r] = 1.0f / ls;
    }
    #pragma unroll
    for (int db = 0; db < 8; db++)
        #pragma unroll
        for (int r = 0; r < 4; r++)
            Ow[(quad * 4 + r) * OSTR + db * 16 + l16] = of[db][r] * inv[r];
    #pragma unroll
    for (int rg = 0; rg < 4; rg++) {
        const int rowl = rg * 4 + quad;
        float* op = out + ((size_t)(b * S_ + wrow0 + rowl)) * E_ + h * HD_;
        #pragma unroll
        for (int u = 0; u < 2; u++) {
            float4 v4 = *(const float4*)&Ow[rowl * OSTR + u * 64 + l16 * 4];
            *(float4*)(op + u * 64 + l16 * 4) = v4;
        }
    }
}

// ---------------------------------------------------------------------------
extern "C" void kernel_launch(void* const* d_in, const int* in_sizes, int n_in,
                              void* d_out, int out_size, void* d_ws, size_t ws_size,
                              hipStream_t stream)
{
    const float* x    = (const float*)d_in[0];   // fp32 (B,S,E)
    const float* W    = (const float*)d_in[1];   // fp32 (6144,2048)
    const float* bias = (const float*)d_in[2];   // fp32 (6144,)
    float* out = (float*)d_out;                  // fp32 (B,S,E)

    const size_t per = (size_t)B_ * NH_ * S_ * HD_;               // 8388608
    unsigned short* qb = (unsigned short*)d_ws;                   // [B][NH][S][HD]
    unsigned short* kb = qb + per;                                // [B][NH][S][HD]
    unsigned short* vb = kb + per;                                // [B][NH][S][HD]
    unsigned short* Xb = vb + per;                                // bf16 X  (16.8 MB)
    unsigned short* Wb = Xb + (size_t)XN_;                        // bf16 W  (25.2 MB)

    const int cvt_elems = XN_ + NQKV_ * E_;                       // 20971520
    cvt_bf16<<<cvt_elems / (256 * 8), 256, 0, stream>>>(x, W, Xb);

    dim3 gemm_grid((M_ / 256) * (NQKV_ / 256));                   // 16*24 = 384
    qkv_gemm<<<gemm_grid, 512, 0, stream>>>(Xb, Wb, bias, qb, kb, vb);

    attn_mfma<<<dim3(32 * 32), 256, 0, stream>>>(qb, kb, vb, out);
}